// Round 1
// baseline (555.301 us; speedup 1.0000x reference)
//
#include <hip/hip_runtime.h>

typedef __attribute__((ext_vector_type(8))) short short8_t;
typedef __attribute__((ext_vector_type(4))) float float4_t;

__device__ __forceinline__ unsigned short f2bf(float f) {
    unsigned int u = __float_as_uint(f);
    return (unsigned short)((u + 0x7FFFu + ((u >> 16) & 1u)) >> 16);
}
__device__ __forceinline__ unsigned int pkbf(float a, float b) {
    return (unsigned int)f2bf(a) | ((unsigned int)f2bf(b) << 16);
}

// ---------------------------------------------------------------------------
// K1: conv1 as implicit GEMM. A = x patches [8192, 4096], B^T = w1 [256,4096].
// Tile 128(M) x 64(N), BK=32, 4 waves 2x2, each wave 64x32 (4x2 16x16 frags).
// K-chunk of 32 = (1 ic, 4 kh, 8 kw) -> A-tile source = 16 full contiguous
// x rows of 256 floats (coalesced float4 loads), converted to bf16 in LDS.
// Epilogue: BN+ReLU -> y bf16 [8192, 256] ([spatial, channel]).
// ---------------------------------------------------------------------------
__global__ __launch_bounds__(256, 1) void k_conv1(
    const float* __restrict__ x, const float* __restrict__ w1,
    const float* __restrict__ s1, const float* __restrict__ b1,
    unsigned short* __restrict__ y)
{
    __shared__ unsigned short At[128 * 40];  // padded stride 40 (80B, 16B-aligned rows)
    __shared__ unsigned short Bt[64 * 40];
    const int tid = threadIdx.x;
    const int nt = blockIdx.x, mt = blockIdx.y;
    const int m0 = mt * 128, n0 = nt * 64;
    const int bi = m0 >> 10;
    const int oh0 = (m0 & 1023) >> 5;
    const int lane = tid & 63, wid = tid >> 6;
    const int wm = wid & 1, wn = wid >> 1;
    const int quad = lane >> 4, r16 = lane & 15;
    const int rA = tid >> 4, segA = tid & 15;   // 16 x-rows, 16 segs of 16 floats
    const int ohl = rA >> 2, khl = rA & 3;
    float4_t acc[4][2] = {};

    for (int k0 = 0; k0 < 4096; k0 += 32) {
        const int ic = k0 >> 6;
        const int kh0 = (k0 >> 3) & 7;  // 0 or 4
        // --- A stage: one contiguous x row per 16 threads ---
        {
            const int xr = (oh0 + ohl) * 8 + kh0 + khl;
            const float* src = x + (((bi * 64 + ic) * 256 + xr) * 256 + segA * 16);
            const float4* s4 = (const float4*)src;
            float4 v0 = s4[0], v1 = s4[1], v2 = s4[2], v3 = s4[3];
            const int dst = (ohl * 32 + segA * 2) * 40 + khl * 8;
            int4 p0, p1;
            p0.x = pkbf(v0.x, v0.y); p0.y = pkbf(v0.z, v0.w);
            p0.z = pkbf(v1.x, v1.y); p0.w = pkbf(v1.z, v1.w);
            p1.x = pkbf(v2.x, v2.y); p1.y = pkbf(v2.z, v2.w);
            p1.z = pkbf(v3.x, v3.y); p1.w = pkbf(v3.z, v3.w);
            *(int4*)&At[dst] = p0;
            *(int4*)&At[dst + 40] = p1;
        }
        // --- B stage: w1 [256,4096] fp32 ---
        #pragma unroll
        for (int j = 0; j < 2; ++j) {
            const int id = j * 256 + tid;
            const int row = id >> 3, p = id & 7;
            float4 v = *(const float4*)(w1 + (n0 + row) * 4096 + k0 + p * 4);
            int2 wv; wv.x = pkbf(v.x, v.y); wv.y = pkbf(v.z, v.w);
            *(int2*)&Bt[row * 40 + p * 4] = wv;
        }
        __syncthreads();
        short8_t aF[4], bF[2];
        #pragma unroll
        for (int i = 0; i < 4; ++i)
            aF[i] = *(const short8_t*)&At[(wm * 64 + i * 16 + r16) * 40 + quad * 8];
        #pragma unroll
        for (int j = 0; j < 2; ++j)
            bF[j] = *(const short8_t*)&Bt[(wn * 32 + j * 16 + r16) * 40 + quad * 8];
        #pragma unroll
        for (int i = 0; i < 4; ++i)
            #pragma unroll
            for (int j = 0; j < 2; ++j)
                acc[i][j] = __builtin_amdgcn_mfma_f32_16x16x32_bf16(aF[i], bF[j], acc[i][j], 0, 0, 0);
        __syncthreads();
    }
    #pragma unroll
    for (int i = 0; i < 4; ++i) {
        const int mg = m0 + wm * 64 + i * 16 + quad * 4;
        #pragma unroll
        for (int j = 0; j < 2; ++j) {
            const int ng = n0 + wn * 32 + j * 16 + r16;
            const float sc = s1[ng], bc = b1[ng];
            #pragma unroll
            for (int r = 0; r < 4; ++r) {
                float v = fmaxf(acc[i][j][r] * sc + bc, 0.f);
                y[(mg + r) * 256 + ng] = f2bf(v);
            }
        }
    }
}

// ---------------------------------------------------------------------------
// K2a: fai|sit projections. A = y bf16 [8192,256], B^T = w_fai/w_sit fp32.
// Tile 128x64. Epilogue BN+ReLU -> P bf16 [8192, 256] (cols 0-127 fai, 128-255 sit).
// ---------------------------------------------------------------------------
__global__ __launch_bounds__(256, 1) void k_proj(
    const unsigned short* __restrict__ y,
    const float* __restrict__ w_fai, const float* __restrict__ w_sit,
    const float* __restrict__ fs, const float* __restrict__ fb,
    const float* __restrict__ ss, const float* __restrict__ sb,
    unsigned short* __restrict__ P)
{
    __shared__ unsigned short At[128 * 40];
    __shared__ unsigned short Bt[64 * 40];
    const int tid = threadIdx.x;
    const int nt = blockIdx.x, mt = blockIdx.y;
    const int m0 = mt * 128, n0 = nt * 64;
    const float* wsrc = (n0 < 128) ? w_fai : w_sit;
    const float* scs  = (n0 < 128) ? fs : ss;
    const float* bcs  = (n0 < 128) ? fb : sb;
    const int noff = n0 & 127;
    const int lane = tid & 63, wid = tid >> 6;
    const int wm = wid & 1, wn = wid >> 1;
    const int quad = lane >> 4, r16 = lane & 15;
    float4_t acc[4][2] = {};

    for (int k0 = 0; k0 < 256; k0 += 32) {
        #pragma unroll
        for (int j = 0; j < 2; ++j) {
            const int id = j * 256 + tid;
            const int row = id >> 2, p = id & 3;
            int4 v = *(const int4*)(y + (m0 + row) * 256 + k0 + p * 8);
            *(int4*)&At[row * 40 + p * 8] = v;
        }
        #pragma unroll
        for (int j = 0; j < 2; ++j) {
            const int id = j * 256 + tid;
            const int row = id >> 3, p = id & 7;
            float4 v = *(const float4*)(wsrc + (noff + row) * 256 + k0 + p * 4);
            int2 wv; wv.x = pkbf(v.x, v.y); wv.y = pkbf(v.z, v.w);
            *(int2*)&Bt[row * 40 + p * 4] = wv;
        }
        __syncthreads();
        short8_t aF[4], bF[2];
        #pragma unroll
        for (int i = 0; i < 4; ++i)
            aF[i] = *(const short8_t*)&At[(wm * 64 + i * 16 + r16) * 40 + quad * 8];
        #pragma unroll
        for (int j = 0; j < 2; ++j)
            bF[j] = *(const short8_t*)&Bt[(wn * 32 + j * 16 + r16) * 40 + quad * 8];
        #pragma unroll
        for (int i = 0; i < 4; ++i)
            #pragma unroll
            for (int j = 0; j < 2; ++j)
                acc[i][j] = __builtin_amdgcn_mfma_f32_16x16x32_bf16(aF[i], bF[j], acc[i][j], 0, 0, 0);
        __syncthreads();
    }
    #pragma unroll
    for (int i = 0; i < 4; ++i) {
        const int mg = m0 + wm * 64 + i * 16 + quad * 4;
        #pragma unroll
        for (int j = 0; j < 2; ++j) {
            const int ng = n0 + wn * 32 + j * 16 + r16;
            const float sc = scs[ng & 127], bc = bcs[ng & 127];
            #pragma unroll
            for (int r = 0; r < 4; ++r) {
                float v = fmaxf(acc[i][j][r] * sc + bc, 0.f);
                P[(mg + r) * 256 + ng] = f2bf(v);
            }
        }
    }
}

// ---------------------------------------------------------------------------
// K2b: gama projection, transposed output. A = w_gama fp32 [128,256],
// B^T = y bf16 [8192,256]. Tile 64x64, wave 32x32. Epilogue BN+ReLU (per-row c!)
// -> G bf16 [8, 128, 1024]  (= B^T layout for the AV GEMM).
// ---------------------------------------------------------------------------
__global__ __launch_bounds__(256, 1) void k_gama(
    const unsigned short* __restrict__ y, const float* __restrict__ wg,
    const float* __restrict__ gs, const float* __restrict__ gb,
    unsigned short* __restrict__ G)
{
    __shared__ unsigned short At[64 * 40];
    __shared__ unsigned short Bt[64 * 40];
    const int tid = threadIdx.x;
    const int nt = blockIdx.x, mt = blockIdx.y;   // nt 0..127 spatial, mt 0..1
    const int m0 = mt * 64, n0 = nt * 64;
    const int lane = tid & 63, wid = tid >> 6;
    const int wm = wid & 1, wn = wid >> 1;
    const int quad = lane >> 4, r16 = lane & 15;
    float4_t acc[2][2] = {};

    for (int k0 = 0; k0 < 256; k0 += 32) {
        #pragma unroll
        for (int j = 0; j < 2; ++j) {
            const int id = j * 256 + tid;
            const int row = id >> 3, p = id & 7;
            float4 v = *(const float4*)(wg + (m0 + row) * 256 + k0 + p * 4);
            int2 wv; wv.x = pkbf(v.x, v.y); wv.y = pkbf(v.z, v.w);
            *(int2*)&At[row * 40 + p * 4] = wv;
        }
        {
            const int row = tid >> 2, p = tid & 3;
            int4 v = *(const int4*)(y + (n0 + row) * 256 + k0 + p * 8);
            *(int4*)&Bt[row * 40 + p * 8] = v;
        }
        __syncthreads();
        short8_t aF[2], bF[2];
        #pragma unroll
        for (int i = 0; i < 2; ++i)
            aF[i] = *(const short8_t*)&At[(wm * 32 + i * 16 + r16) * 40 + quad * 8];
        #pragma unroll
        for (int j = 0; j < 2; ++j)
            bF[j] = *(const short8_t*)&Bt[(wn * 32 + j * 16 + r16) * 40 + quad * 8];
        #pragma unroll
        for (int i = 0; i < 2; ++i)
            #pragma unroll
            for (int j = 0; j < 2; ++j)
                acc[i][j] = __builtin_amdgcn_mfma_f32_16x16x32_bf16(aF[i], bF[j], acc[i][j], 0, 0, 0);
        __syncthreads();
    }
    #pragma unroll
    for (int i = 0; i < 2; ++i) {
        const int cbase = m0 + wm * 32 + i * 16 + quad * 4;
        #pragma unroll
        for (int j = 0; j < 2; ++j) {
            const int ngg = n0 + wn * 32 + j * 16 + r16;   // global spatial 0..8191
            const int nb = ngg >> 10, msp = ngg & 1023;
            #pragma unroll
            for (int r = 0; r < 4; ++r) {
                const int c = cbase + r;
                float v = fmaxf(acc[i][j][r] * gs[c] + gb[c], 0.f);
                G[(nb * 128 + c) * 1024 + msp] = f2bf(v);
            }
        }
    }
}

// ---------------------------------------------------------------------------
// K3a: logits + sigmoid. Per batch: A = fai (P cols 0-127), B^T = sit (P cols
// 128-255), K=128. Tile 128x64 -> sf bf16 [8, 1024(n), 1024(m)].
// ---------------------------------------------------------------------------
__global__ __launch_bounds__(256, 1) void k_logits(
    const unsigned short* __restrict__ P, unsigned short* __restrict__ sf)
{
    __shared__ unsigned short At[128 * 40];
    __shared__ unsigned short Bt[64 * 40];
    const int tid = threadIdx.x;
    const int nt = blockIdx.x, mt = blockIdx.y, b = blockIdx.z;
    const int m0 = mt * 128, n0 = nt * 64;
    const int base = b * 1024;
    const int lane = tid & 63, wid = tid >> 6;
    const int wm = wid & 1, wn = wid >> 1;
    const int quad = lane >> 4, r16 = lane & 15;
    float4_t acc[4][2] = {};

    for (int k0 = 0; k0 < 128; k0 += 32) {
        #pragma unroll
        for (int j = 0; j < 2; ++j) {
            const int id = j * 256 + tid;
            const int row = id >> 2, p = id & 3;
            int4 v = *(const int4*)(P + (base + m0 + row) * 256 + k0 + p * 8);
            *(int4*)&At[row * 40 + p * 8] = v;
        }
        {
            const int row = tid >> 2, p = tid & 3;
            int4 v = *(const int4*)(P + (base + n0 + row) * 256 + 128 + k0 + p * 8);
            *(int4*)&Bt[row * 40 + p * 8] = v;
        }
        __syncthreads();
        short8_t aF[4], bF[2];
        #pragma unroll
        for (int i = 0; i < 4; ++i)
            aF[i] = *(const short8_t*)&At[(wm * 64 + i * 16 + r16) * 40 + quad * 8];
        #pragma unroll
        for (int j = 0; j < 2; ++j)
            bF[j] = *(const short8_t*)&Bt[(wn * 32 + j * 16 + r16) * 40 + quad * 8];
        #pragma unroll
        for (int i = 0; i < 4; ++i)
            #pragma unroll
            for (int j = 0; j < 2; ++j)
                acc[i][j] = __builtin_amdgcn_mfma_f32_16x16x32_bf16(aF[i], bF[j], acc[i][j], 0, 0, 0);
        __syncthreads();
    }
    #pragma unroll
    for (int i = 0; i < 4; ++i) {
        const int mg = m0 + wm * 64 + i * 16 + quad * 4;
        #pragma unroll
        for (int j = 0; j < 2; ++j) {
            const int ng = n0 + wn * 32 + j * 16 + r16;
            #pragma unroll
            for (int r = 0; r < 4; ++r) {
                float v = 1.0f / (1.0f + expf(-acc[i][j][r]));
                sf[b * 1048576 + (mg + r) * 1024 + ng] = f2bf(v);
            }
        }
    }
}

// ---------------------------------------------------------------------------
// K3b: out = sf . gama^T. Per batch: A = sf [1024,1024] bf16, B^T = G[b]
// [128,1024] bf16, K=1024. Tile 64x64, wave 32x32 -> O fp32 [8, 1024(n), 128(c)].
// ---------------------------------------------------------------------------
__global__ __launch_bounds__(256, 1) void k_av(
    const unsigned short* __restrict__ sf, const unsigned short* __restrict__ G,
    float* __restrict__ O)
{
    __shared__ unsigned short At[64 * 40];
    __shared__ unsigned short Bt[64 * 40];
    const int tid = threadIdx.x;
    const int nt = blockIdx.x, mt = blockIdx.y, b = blockIdx.z;  // nt 0..1, mt 0..15
    const int m0 = mt * 64, n0 = nt * 64;
    const int lane = tid & 63, wid = tid >> 6;
    const int wm = wid & 1, wn = wid >> 1;
    const int quad = lane >> 4, r16 = lane & 15;
    float4_t acc[2][2] = {};

    for (int k0 = 0; k0 < 1024; k0 += 32) {
        {
            const int row = tid >> 2, p = tid & 3;
            int4 v = *(const int4*)(sf + b * 1048576 + (m0 + row) * 1024 + k0 + p * 8);
            *(int4*)&At[row * 40 + p * 8] = v;
            int4 v2 = *(const int4*)(G + (b * 128 + n0 + row) * 1024 + k0 + p * 8);
            *(int4*)&Bt[row * 40 + p * 8] = v2;
        }
        __syncthreads();
        short8_t aF[2], bF[2];
        #pragma unroll
        for (int i = 0; i < 2; ++i)
            aF[i] = *(const short8_t*)&At[(wm * 32 + i * 16 + r16) * 40 + quad * 8];
        #pragma unroll
        for (int j = 0; j < 2; ++j)
            bF[j] = *(const short8_t*)&Bt[(wn * 32 + j * 16 + r16) * 40 + quad * 8];
        #pragma unroll
        for (int i = 0; i < 2; ++i)
            #pragma unroll
            for (int j = 0; j < 2; ++j)
                acc[i][j] = __builtin_amdgcn_mfma_f32_16x16x32_bf16(aF[i], bF[j], acc[i][j], 0, 0, 0);
        __syncthreads();
    }
    #pragma unroll
    for (int i = 0; i < 2; ++i) {
        const int mg = m0 + wm * 32 + i * 16 + quad * 4;
        #pragma unroll
        for (int j = 0; j < 2; ++j) {
            const int ng = n0 + wn * 32 + j * 16 + r16;
            #pragma unroll
            for (int r = 0; r < 4; ++r)
                O[b * 131072 + (mg + r) * 128 + ng] = acc[i][j][r];
        }
    }
}

// ---------------------------------------------------------------------------
// K4: bilinear x8 upsample, align_corners. Block = (y, b); stage O rows y0,y1
// (32 xs x 128 c each) in LDS (padded stride 136 vs bank-aliasing), thread=x.
// ---------------------------------------------------------------------------
__global__ __launch_bounds__(256, 1) void k_up(
    const float* __restrict__ O, float* __restrict__ out)
{
    __shared__ float l0[32 * 136];
    __shared__ float l1[32 * 136];
    const int tid = threadIdx.x;
    const int yb = blockIdx.x, b = blockIdx.y;
    const float sc = 31.0f / 255.0f;
    const float fy = yb * sc;
    const int y0 = (int)fy;
    const float wy = fy - (float)y0;
    const int y1 = min(y0 + 1, 31);
    const float4* r0 = (const float4*)(O + b * 131072 + y0 * 4096);
    const float4* r1 = (const float4*)(O + b * 131072 + y1 * 4096);
    #pragma unroll
    for (int j = 0; j < 4; ++j) {
        const int id = j * 256 + tid;       // 0..1023 float4 chunks
        const int xs = id >> 5, c4 = id & 31;
        *(float4*)(l0 + xs * 136 + c4 * 4) = r0[id];
        *(float4*)(l1 + xs * 136 + c4 * 4) = r1[id];
    }
    __syncthreads();
    const float fx = tid * sc;
    const int x0 = (int)fx;
    const float wx = fx - (float)x0;
    const int x1 = min(x0 + 1, 31);
    const float w00 = (1.f - wy) * (1.f - wx), w01 = (1.f - wy) * wx;
    const float w10 = wy * (1.f - wx), w11 = wy * wx;
    const float* a = l0 + x0 * 136;
    const float* bq = l0 + x1 * 136;
    const float* c = l1 + x0 * 136;
    const float* d = l1 + x1 * 136;
    float* op = out + b * 8388608 + yb * 256 + tid;
    #pragma unroll 4
    for (int ch = 0; ch < 128; ++ch)
        op[ch * 65536] = w00 * a[ch] + w01 * bq[ch] + w10 * c[ch] + w11 * d[ch];
}

extern "C" void kernel_launch(void* const* d_in, const int* in_sizes, int n_in,
                              void* d_out, int out_size, void* d_ws, size_t ws_size,
                              hipStream_t stream) {
    (void)in_sizes; (void)n_in; (void)out_size; (void)ws_size;
    const float* x      = (const float*)d_in[0];
    const float* w1     = (const float*)d_in[1];
    const float* bn1_s  = (const float*)d_in[2];
    const float* bn1_b  = (const float*)d_in[3];
    const float* w_fai  = (const float*)d_in[4];
    const float* bnf_s  = (const float*)d_in[5];
    const float* bnf_b  = (const float*)d_in[6];
    const float* w_sit  = (const float*)d_in[7];
    const float* bns_s  = (const float*)d_in[8];
    const float* bns_b  = (const float*)d_in[9];
    const float* w_gama = (const float*)d_in[10];
    const float* bng_s  = (const float*)d_in[11];
    const float* bng_b  = (const float*)d_in[12];
    float* out = (float*)d_out;

    char* ws = (char*)d_ws;
    unsigned short* y  = (unsigned short*)(ws);                       // 4 MB  [8192,256]
    unsigned short* P  = (unsigned short*)(ws + 4u * 1024 * 1024);    // 4 MB  [8192,256]
    unsigned short* G  = (unsigned short*)(ws + 8u * 1024 * 1024);    // 2 MB  [8,128,1024]
    unsigned short* sf = (unsigned short*)(ws + 10u * 1024 * 1024);   // 16 MB [8,1024,1024]
    float*          O  = (float*)(ws + 26u * 1024 * 1024);            // 4 MB  [8,1024,128]

    k_conv1 <<<dim3(4, 64),    256, 0, stream>>>(x, w1, bn1_s, bn1_b, y);
    k_proj  <<<dim3(4, 64),    256, 0, stream>>>(y, w_fai, w_sit, bnf_s, bnf_b, bns_s, bns_b, P);
    k_gama  <<<dim3(128, 2),   256, 0, stream>>>(y, w_gama, bng_s, bng_b, G);
    k_logits<<<dim3(16, 8, 8), 256, 0, stream>>>(P, sf);
    k_av    <<<dim3(2, 16, 8), 256, 0, stream>>>(sf, G, O);
    k_up    <<<dim3(256, 8),   256, 0, stream>>>(O, out);
}

// Round 2
// 494.048 us; speedup vs baseline: 1.1240x; 1.1240x over previous
//
#include <hip/hip_runtime.h>

typedef __attribute__((ext_vector_type(8))) short short8_t;
typedef __attribute__((ext_vector_type(4))) float float4_t;

__device__ __forceinline__ unsigned short f2bf(float f) {
    unsigned int u = __float_as_uint(f);
    return (unsigned short)((u + 0x7FFFu + ((u >> 16) & 1u)) >> 16);
}
__device__ __forceinline__ unsigned int pkbf(float a, float b) {
    return (unsigned int)f2bf(a) | ((unsigned int)f2bf(b) << 16);
}

// ---------------------------------------------------------------------------
// K1: conv1 implicit GEMM, tile 128(M) x 256(N full), split-K x4.
// 512 threads = 8 waves (2m x 4n), wave 64x64, BK=32, register prefetch-1.
// Threads 0-255 stage A (x patches, fp32->bf16), 256-511 stage B (w1).
// A-LDS uses XOR swizzle on the k-offset: koff = (khl ^ ((row>>1)&3))*8.
// Output: fp32 partials part[kc][8192][256].
// ---------------------------------------------------------------------------
__global__ __launch_bounds__(512, 2) void k_conv1(
    const float* __restrict__ x, const float* __restrict__ w1,
    float* __restrict__ part)
{
    __shared__ unsigned short At[128 * 40];
    __shared__ unsigned short Bt[256 * 40];
    const int tid = threadIdx.x;
    const int mt = blockIdx.x, kc = blockIdx.y;
    const int m0 = mt * 128;
    const int bi = mt >> 3;
    const int oh0 = (mt & 7) * 4;
    const int lane = tid & 63, wid = tid >> 6;
    const int wm = wid & 1, wn = wid >> 1;          // 2 x 4 waves
    const int quad = lane >> 4, r16 = lane & 15;
    const bool isA = tid < 256;
    const int tA = tid & 255;
    const int rA = tA >> 4, segA = tA & 15;
    const int ohl = rA >> 2, khl = rA & 3;
    const int rowA = ohl * 32 + segA * 2;
    const int koffA = (khl ^ (segA & 3)) * 8;       // swizzled k-offset (shorts)
    const int kbase = kc * 1024;
    float4_t acc[4][4] = {};
    float4 ra[4];   // A prefetch regs
    float4 rb[8];   // B prefetch regs

    // prefetch iter 0
    if (isA) {
        const int ic = kbase >> 6, kh0 = (kbase >> 3) & 7;
        const int xr = (oh0 + ohl) * 8 + kh0 + khl;
        const float4* s4 = (const float4*)(x + (((bi * 64 + ic) * 256 + xr) * 256 + segA * 16));
        ra[0] = s4[0]; ra[1] = s4[1]; ra[2] = s4[2]; ra[3] = s4[3];
    } else {
        #pragma unroll
        for (int l = 0; l < 8; ++l) {
            const int slot = l * 256 + tA;
            const int row = slot >> 3, p = slot & 7;
            rb[l] = *(const float4*)(w1 + row * 4096 + kbase + p * 4);
        }
    }

    for (int it = 0; it < 32; ++it) {
        // ---- commit prefetched regs to LDS ----
        if (isA) {
            int4 p0, p1;
            p0.x = pkbf(ra[0].x, ra[0].y); p0.y = pkbf(ra[0].z, ra[0].w);
            p0.z = pkbf(ra[1].x, ra[1].y); p0.w = pkbf(ra[1].z, ra[1].w);
            p1.x = pkbf(ra[2].x, ra[2].y); p1.y = pkbf(ra[2].z, ra[2].w);
            p1.z = pkbf(ra[3].x, ra[3].y); p1.w = pkbf(ra[3].z, ra[3].w);
            *(int4*)&At[rowA * 40 + koffA] = p0;
            *(int4*)&At[(rowA + 1) * 40 + koffA] = p1;
        } else {
            #pragma unroll
            for (int l = 0; l < 8; ++l) {
                const int slot = l * 256 + tA;
                const int row = slot >> 3, p = slot & 7;
                int2 wv; wv.x = pkbf(rb[l].x, rb[l].y); wv.y = pkbf(rb[l].z, rb[l].w);
                *(int2*)&Bt[row * 40 + p * 4] = wv;
            }
        }
        __syncthreads();
        // ---- issue next iter's global loads (overlap with MFMA below) ----
        if (it + 1 < 32) {
            const int k0 = kbase + (it + 1) * 32;
            if (isA) {
                const int ic = k0 >> 6, kh0 = (k0 >> 3) & 7;
                const int xr = (oh0 + ohl) * 8 + kh0 + khl;
                const float4* s4 = (const float4*)(x + (((bi * 64 + ic) * 256 + xr) * 256 + segA * 16));
                ra[0] = s4[0]; ra[1] = s4[1]; ra[2] = s4[2]; ra[3] = s4[3];
            } else {
                #pragma unroll
                for (int l = 0; l < 8; ++l) {
                    const int slot = l * 256 + tA;
                    const int row = slot >> 3, p = slot & 7;
                    rb[l] = *(const float4*)(w1 + row * 4096 + k0 + p * 4);
                }
            }
        }
        // ---- MFMA phase ----
        short8_t aF[4], bF[4];
        #pragma unroll
        for (int i = 0; i < 4; ++i) {
            const int R = wm * 64 + i * 16 + r16;
            aF[i] = *(const short8_t*)&At[R * 40 + (quad ^ ((r16 >> 1) & 3)) * 8];
        }
        #pragma unroll
        for (int j = 0; j < 4; ++j)
            bF[j] = *(const short8_t*)&Bt[(wn * 64 + j * 16 + r16) * 40 + quad * 8];
        #pragma unroll
        for (int i = 0; i < 4; ++i)
            #pragma unroll
            for (int j = 0; j < 4; ++j)
                acc[i][j] = __builtin_amdgcn_mfma_f32_16x16x32_bf16(aF[i], bF[j], acc[i][j], 0, 0, 0);
        __syncthreads();
    }
    float* pp = part + ((size_t)kc << 21);
    #pragma unroll
    for (int i = 0; i < 4; ++i) {
        const int mg = m0 + wm * 64 + i * 16 + quad * 4;
        #pragma unroll
        for (int j = 0; j < 4; ++j) {
            const int ng = wn * 64 + j * 16 + r16;
            #pragma unroll
            for (int r = 0; r < 4; ++r)
                pp[(mg + r) * 256 + ng] = acc[i][j][r];
        }
    }
}

// ---------------------------------------------------------------------------
// K1b: reduce 4 split-K partials + BN + ReLU -> y bf16 [8192,256].
// ---------------------------------------------------------------------------
__global__ __launch_bounds__(256, 4) void k_reduce(
    const float* __restrict__ part, const float* __restrict__ s1,
    const float* __restrict__ b1, unsigned short* __restrict__ y)
{
    const int id = blockIdx.x * 256 + threadIdx.x;   // 0..524287 float4 slots
    const int c4 = id & 63;
    const float4* p = (const float4*)part + id;
    float4 a = p[0], b = p[524288], c = p[1048576], d = p[1572864];
    float4 s = ((const float4*)s1)[c4], bb = ((const float4*)b1)[c4];
    float vx = fmaxf((a.x + b.x + c.x + d.x) * s.x + bb.x, 0.f);
    float vy = fmaxf((a.y + b.y + c.y + d.y) * s.y + bb.y, 0.f);
    float vz = fmaxf((a.z + b.z + c.z + d.z) * s.z + bb.z, 0.f);
    float vw = fmaxf((a.w + b.w + c.w + d.w) * s.w + bb.w, 0.f);
    int2 o; o.x = pkbf(vx, vy); o.y = pkbf(vz, vw);
    ((int2*)y)[id] = o;
}

// ---------------------------------------------------------------------------
// K2: fused fai/sit/gama projections. A = y bf16 [8192,256], B^T selected
// from {w_fai,w_sit,w_gama} by nt (0-5). Tile 64x64, 4 waves 2x2, K=256.
// nt<4 -> P bf16 [8192,256] (cols 0-127 fai, 128-255 sit);
// nt>=4 -> G bf16 [8,128,1024] (transposed, for the AV GEMM B-operand).
// ---------------------------------------------------------------------------
__global__ __launch_bounds__(256, 2) void k_proj3(
    const unsigned short* __restrict__ y,
    const float* __restrict__ w_fai, const float* __restrict__ w_sit,
    const float* __restrict__ w_gama,
    const float* __restrict__ fs, const float* __restrict__ fb,
    const float* __restrict__ ss, const float* __restrict__ sb,
    const float* __restrict__ gs, const float* __restrict__ gb,
    unsigned short* __restrict__ P, unsigned short* __restrict__ G)
{
    __shared__ unsigned short At[64 * 40];
    __shared__ unsigned short Bt[64 * 40];
    const int tid = threadIdx.x;
    const int nt = blockIdx.x, mt = blockIdx.y;
    const int m0 = mt * 64;
    const float *W, *S, *Bb;
    if (nt < 2)      { W = w_fai;  S = fs; Bb = fb; }
    else if (nt < 4) { W = w_sit;  S = ss; Bb = sb; }
    else             { W = w_gama; S = gs; Bb = gb; }
    const int roff = (nt * 64) & 127;
    const int lane = tid & 63, wid = tid >> 6;
    const int wm = wid & 1, wn = wid >> 1;
    const int quad = lane >> 4, r16 = lane & 15;
    float4_t acc[2][2] = {};

    for (int k0 = 0; k0 < 256; k0 += 32) {
        {   // A: y tile 64x32 bf16, direct copy
            const int row = tid >> 2, pp = tid & 3;
            *(int4*)&At[row * 40 + pp * 8] =
                *(const int4*)(y + (m0 + row) * 256 + k0 + pp * 8);
        }
        #pragma unroll
        for (int l = 0; l < 2; ++l) {   // B: W tile 64x32 fp32 -> bf16
            const int slot = l * 256 + tid;
            const int row = slot >> 3, pp = slot & 7;
            float4 v = *(const float4*)(W + (roff + row) * 256 + k0 + pp * 4);
            int2 wv; wv.x = pkbf(v.x, v.y); wv.y = pkbf(v.z, v.w);
            *(int2*)&Bt[row * 40 + pp * 4] = wv;
        }
        __syncthreads();
        short8_t aF[2], bF[2];
        #pragma unroll
        for (int i = 0; i < 2; ++i)
            aF[i] = *(const short8_t*)&At[(wm * 32 + i * 16 + r16) * 40 + quad * 8];
        #pragma unroll
        for (int j = 0; j < 2; ++j)
            bF[j] = *(const short8_t*)&Bt[(wn * 32 + j * 16 + r16) * 40 + quad * 8];
        #pragma unroll
        for (int i = 0; i < 2; ++i)
            #pragma unroll
            for (int j = 0; j < 2; ++j)
                acc[i][j] = __builtin_amdgcn_mfma_f32_16x16x32_bf16(aF[i], bF[j], acc[i][j], 0, 0, 0);
        __syncthreads();
    }
    #pragma unroll
    for (int i = 0; i < 2; ++i) {
        const int mg = m0 + wm * 32 + i * 16 + quad * 4;
        #pragma unroll
        for (int j = 0; j < 2; ++j) {
            const int nl = wn * 32 + j * 16 + r16;
            const float sc = S[roff + nl], bc = Bb[roff + nl];
            if (nt < 4) {
                const int col = nt * 64 + nl;
                #pragma unroll
                for (int r = 0; r < 4; ++r) {
                    float v = fmaxf(acc[i][j][r] * sc + bc, 0.f);
                    P[(mg + r) * 256 + col] = f2bf(v);
                }
            } else {
                const int c = roff + nl;
                #pragma unroll
                for (int r = 0; r < 4; ++r) {
                    float v = fmaxf(acc[i][j][r] * sc + bc, 0.f);
                    const int sp = mg + r;
                    G[((sp >> 10) * 128 + c) * 1024 + (sp & 1023)] = f2bf(v);
                }
            }
        }
    }
}

// ---------------------------------------------------------------------------
// K3: logits + sigmoid. A = fai (P cols 0-127), B^T = sit (P cols 128-255),
// K=128. Tile 128x64 -> sf bf16 [8,1024,1024].
// ---------------------------------------------------------------------------
__global__ __launch_bounds__(256, 2) void k_logits(
    const unsigned short* __restrict__ P, unsigned short* __restrict__ sf)
{
    __shared__ unsigned short At[128 * 40];
    __shared__ unsigned short Bt[64 * 40];
    const int tid = threadIdx.x;
    const int nt = blockIdx.x, mt = blockIdx.y, b = blockIdx.z;
    const int m0 = mt * 128, n0 = nt * 64;
    const int base = b * 1024;
    const int lane = tid & 63, wid = tid >> 6;
    const int wm = wid & 1, wn = wid >> 1;
    const int quad = lane >> 4, r16 = lane & 15;
    float4_t acc[4][2] = {};

    for (int k0 = 0; k0 < 128; k0 += 32) {
        #pragma unroll
        for (int j = 0; j < 2; ++j) {
            const int id = j * 256 + tid;
            const int row = id >> 2, p = id & 3;
            *(int4*)&At[row * 40 + p * 8] =
                *(const int4*)(P + (base + m0 + row) * 256 + k0 + p * 8);
        }
        {
            const int row = tid >> 2, p = tid & 3;
            *(int4*)&Bt[row * 40 + p * 8] =
                *(const int4*)(P + (base + n0 + row) * 256 + 128 + k0 + p * 8);
        }
        __syncthreads();
        short8_t aF[4], bF[2];
        #pragma unroll
        for (int i = 0; i < 4; ++i)
            aF[i] = *(const short8_t*)&At[(wm * 64 + i * 16 + r16) * 40 + quad * 8];
        #pragma unroll
        for (int j = 0; j < 2; ++j)
            bF[j] = *(const short8_t*)&Bt[(wn * 32 + j * 16 + r16) * 40 + quad * 8];
        #pragma unroll
        for (int i = 0; i < 4; ++i)
            #pragma unroll
            for (int j = 0; j < 2; ++j)
                acc[i][j] = __builtin_amdgcn_mfma_f32_16x16x32_bf16(aF[i], bF[j], acc[i][j], 0, 0, 0);
        __syncthreads();
    }
    #pragma unroll
    for (int i = 0; i < 4; ++i) {
        const int mg = m0 + wm * 64 + i * 16 + quad * 4;
        #pragma unroll
        for (int j = 0; j < 2; ++j) {
            const int ng = n0 + wn * 32 + j * 16 + r16;
            #pragma unroll
            for (int r = 0; r < 4; ++r) {
                float v = 1.0f / (1.0f + expf(-acc[i][j][r]));
                sf[b * 1048576 + (mg + r) * 1024 + ng] = f2bf(v);
            }
        }
    }
}

// ---------------------------------------------------------------------------
// K4: out = sf . gama^T, split-K x4. Tile 64(m) x 128(ch, full), 4 waves 2x2
// (wave 32x64). Grid (16 mt, 32 = b*4+kc). Partials Opart[kc][8][1024][128].
// ---------------------------------------------------------------------------
__global__ __launch_bounds__(256, 2) void k_av(
    const unsigned short* __restrict__ sf, const unsigned short* __restrict__ G,
    float* __restrict__ Opart)
{
    __shared__ unsigned short At[64 * 40];
    __shared__ unsigned short Bt[128 * 40];
    const int tid = threadIdx.x;
    const int mt = blockIdx.x, zz = blockIdx.y;
    const int b = zz >> 2, kc = zz & 3;
    const int m0 = mt * 64;
    const int lane = tid & 63, wid = tid >> 6;
    const int wm = wid & 1, wn = wid >> 1;
    const int quad = lane >> 4, r16 = lane & 15;
    float4_t acc[2][4] = {};

    for (int it = 0; it < 8; ++it) {
        const int k0 = kc * 256 + it * 32;
        {
            const int row = tid >> 2, p = tid & 3;
            *(int4*)&At[row * 40 + p * 8] =
                *(const int4*)(sf + b * 1048576 + (m0 + row) * 1024 + k0 + p * 8);
        }
        #pragma unroll
        for (int l = 0; l < 2; ++l) {
            const int slot = l * 256 + tid;
            const int row = slot >> 2, p = slot & 3;
            *(int4*)&Bt[row * 40 + p * 8] =
                *(const int4*)(G + (b * 128 + row) * 1024 + k0 + p * 8);
        }
        __syncthreads();
        short8_t aF[2], bF[4];
        #pragma unroll
        for (int i = 0; i < 2; ++i)
            aF[i] = *(const short8_t*)&At[(wm * 32 + i * 16 + r16) * 40 + quad * 8];
        #pragma unroll
        for (int j = 0; j < 4; ++j)
            bF[j] = *(const short8_t*)&Bt[(wn * 64 + j * 16 + r16) * 40 + quad * 8];
        #pragma unroll
        for (int i = 0; i < 2; ++i)
            #pragma unroll
            for (int j = 0; j < 4; ++j)
                acc[i][j] = __builtin_amdgcn_mfma_f32_16x16x32_bf16(aF[i], bF[j], acc[i][j], 0, 0, 0);
        __syncthreads();
    }
    float* op = Opart + (size_t)kc * 1048576 + (size_t)b * 131072;
    #pragma unroll
    for (int i = 0; i < 2; ++i) {
        const int mg = m0 + wm * 32 + i * 16 + quad * 4;
        #pragma unroll
        for (int j = 0; j < 4; ++j) {
            const int ng = wn * 64 + j * 16 + r16;
            #pragma unroll
            for (int r = 0; r < 4; ++r)
                op[(mg + r) * 128 + ng] = acc[i][j][r];
        }
    }
}

// ---------------------------------------------------------------------------
// K5: sum 4 O-partials + bilinear x8 upsample (align_corners).
// ---------------------------------------------------------------------------
__global__ __launch_bounds__(256, 2) void k_up(
    const float* __restrict__ Opart, float* __restrict__ out)
{
    __shared__ float l0[32 * 136];
    __shared__ float l1[32 * 136];
    const int tid = threadIdx.x;
    const int yb = blockIdx.x, b = blockIdx.y;
    const float sc = 31.0f / 255.0f;
    const float fy = yb * sc;
    const int y0 = (int)fy;
    const float wy = fy - (float)y0;
    const int y1 = (y0 + 1 < 32) ? y0 + 1 : 31;
    const float4* r0 = (const float4*)(Opart + (size_t)b * 131072 + y0 * 4096);
    const float4* r1 = (const float4*)(Opart + (size_t)b * 131072 + y1 * 4096);
    #pragma unroll
    for (int j = 0; j < 4; ++j) {
        const int id = j * 256 + tid;       // 0..1023 float4 chunks of a row
        const int xs = id >> 5, c4 = id & 31;
        float4 a0 = r0[id], a1 = r1[id];
        #pragma unroll
        for (int kc = 1; kc < 4; ++kc) {
            float4 t0 = r0[id + kc * 262144], t1 = r1[id + kc * 262144];
            a0.x += t0.x; a0.y += t0.y; a0.z += t0.z; a0.w += t0.w;
            a1.x += t1.x; a1.y += t1.y; a1.z += t1.z; a1.w += t1.w;
        }
        *(float4*)(l0 + xs * 136 + c4 * 4) = a0;
        *(float4*)(l1 + xs * 136 + c4 * 4) = a1;
    }
    __syncthreads();
    const float fx = tid * sc;
    const int x0 = (int)fx;
    const float wx = fx - (float)x0;
    const int x1 = (x0 + 1 < 32) ? x0 + 1 : 31;
    const float w00 = (1.f - wy) * (1.f - wx), w01 = (1.f - wy) * wx;
    const float w10 = wy * (1.f - wx), w11 = wy * wx;
    const float* a = l0 + x0 * 136;
    const float* bq = l0 + x1 * 136;
    const float* c = l1 + x0 * 136;
    const float* d = l1 + x1 * 136;
    float* op = out + (size_t)b * 8388608 + yb * 256 + tid;
    #pragma unroll 4
    for (int ch = 0; ch < 128; ++ch)
        op[ch * 65536] = w00 * a[ch] + w01 * bq[ch] + w10 * c[ch] + w11 * d[ch];
}

extern "C" void kernel_launch(void* const* d_in, const int* in_sizes, int n_in,
                              void* d_out, int out_size, void* d_ws, size_t ws_size,
                              hipStream_t stream) {
    (void)in_sizes; (void)n_in; (void)out_size; (void)ws_size;
    const float* x      = (const float*)d_in[0];
    const float* w1     = (const float*)d_in[1];
    const float* bn1_s  = (const float*)d_in[2];
    const float* bn1_b  = (const float*)d_in[3];
    const float* w_fai  = (const float*)d_in[4];
    const float* bnf_s  = (const float*)d_in[5];
    const float* bnf_b  = (const float*)d_in[6];
    const float* w_sit  = (const float*)d_in[7];
    const float* bns_s  = (const float*)d_in[8];
    const float* bns_b  = (const float*)d_in[9];
    const float* w_gama = (const float*)d_in[10];
    const float* bng_s  = (const float*)d_in[11];
    const float* bng_b  = (const float*)d_in[12];
    float* out = (float*)d_out;

    char* ws = (char*)d_ws;
    // region [0,32MB): conv partials, then (after k_reduce) reused:
    //   sf  @ 0      (16 MB)   Opart @ 16MB (16 MB)
    float*          pc    = (float*)ws;                              // [4][8192][256]
    unsigned short* sf    = (unsigned short*)ws;                     // [8][1024][1024]
    float*          Opart = (float*)(ws + 16u * 1024 * 1024);        // [4][8][1024][128]
    unsigned short* y     = (unsigned short*)(ws + 32u * 1024 * 1024);  // 4 MB
    unsigned short* P     = (unsigned short*)(ws + 36u * 1024 * 1024);  // 4 MB
    unsigned short* G     = (unsigned short*)(ws + 40u * 1024 * 1024);  // 2 MB

    k_conv1 <<<dim3(64, 4),    512, 0, stream>>>(x, w1, pc);
    k_reduce<<<dim3(2048),     256, 0, stream>>>(pc, bn1_s, bn1_b, y);
    k_proj3 <<<dim3(6, 128),   256, 0, stream>>>(y, w_fai, w_sit, w_gama,
                                                 bnf_s, bnf_b, bns_s, bns_b,
                                                 bng_s, bng_b, P, G);
    k_logits<<<dim3(16, 8, 8), 256, 0, stream>>>(P, sf);
    k_av    <<<dim3(16, 32),   256, 0, stream>>>(sf, G, Opart);
    k_up    <<<dim3(256, 8),   256, 0, stream>>>(Opart, out);
}